// Round 13
// baseline (121.764 us; speedup 1.0000x reference)
//
#include <hip/hip_runtime.h>
#include <cstdint>
#include <cstddef>

#define N_NODES 8192
#define IN_DIM 128
#define H 32
#define KB 8192          // path-2 buckets
#define NCH 66           // 32 E*Wh + 32 F*Wh + E + F channels
#define RSH 32.0f        // conservative shift: |s| << 32 by construction

typedef __attribute__((ext_vector_type(8))) short short8;
typedef __attribute__((ext_vector_type(4))) float f32x4;

__device__ __forceinline__ float sigmoidf_(float x) { return 1.0f / (1.0f + __expf(-x)); }
__device__ __forceinline__ float tanh_fast(float x) { return 1.0f - 2.0f / (1.0f + __expf(2.0f * x)); }
__device__ __forceinline__ unsigned short f2bf(float f) {
    unsigned u = __float_as_uint(f);
    unsigned r = (u + 0x7fffu + ((u >> 16) & 1u)) >> 16;
    return (unsigned short)r;
}
__device__ __forceinline__ unsigned pack_bf_pair(float lo, float hi) {
    unsigned a = __float_as_uint(lo) + 0x7FFFu;
    unsigned b = __float_as_uint(hi) + 0x7FFFu;
    return __builtin_amdgcn_perm(b, a, 0x07060302u);
}

// ---------------------------------------------------------------------------
// Node 1 — K1: Wh = x@W^T + b both paths. WhT1 bf16 (H x N) for MFMA;
// Wh2T f32 (H x N) for the channel scan; s = Wh@a. Block 0 zeroes wsum.
// ---------------------------------------------------------------------------
__global__ __launch_bounds__(256) void k1_wh_s(
    const float* __restrict__ x,
    const float* __restrict__ W1, const float* __restrict__ b1, const float* __restrict__ a1,
    const float* __restrict__ W2, const float* __restrict__ b2, const float* __restrict__ a2,
    unsigned short* __restrict__ WhT1, float* __restrict__ Wh2T,
    float* __restrict__ s1, float* __restrict__ s2, float* __restrict__ wsum)
{
    __shared__ float xl[8 * IN_DIM];
    __shared__ __align__(16) unsigned short t1[32][8];
    __shared__ __align__(16) float t2f[32][8];
    int tid = threadIdx.x;
    int row0 = blockIdx.x * 8;

    if (blockIdx.x == 0 && tid < 2) wsum[tid] = 0.f;

    ((float4*)xl)[tid] = ((const float4*)(x + (size_t)row0 * IN_DIM))[tid];
    __syncthreads();

    int r = tid >> 5, h = tid & 31;
    const float* xr = xl + r * IN_DIM;
    const float* w1r = W1 + h * IN_DIM;
    const float* w2r = W2 + h * IN_DIM;
    float d1 = 0.f, d2 = 0.f;
#pragma unroll 8
    for (int k = 0; k < IN_DIM; k += 4) {
        float4 xv = *(const float4*)(xr + k);
        float4 wa = *(const float4*)(w1r + k);
        float4 wb = *(const float4*)(w2r + k);
        d1 += xv.x * wa.x + xv.y * wa.y + xv.z * wa.z + xv.w * wa.w;
        d2 += xv.x * wb.x + xv.y * wb.y + xv.z * wb.z + xv.w * wb.w;
    }
    int grow = row0 + r;
    float wh1 = d1 + b1[h];
    float wh2 = d2 + b2[h];
    t1[h][r] = f2bf(wh1);
    t2f[h][r] = wh2;

    float v1 = wh1 * a1[h];
    float v2 = wh2 * a2[h];
#pragma unroll
    for (int m = 16; m >= 1; m >>= 1) { v1 += __shfl_xor(v1, m); v2 += __shfl_xor(v2, m); }
    if (h == 0) { s1[grow] = v1; s2[grow] = v2; }
    __syncthreads();

    if (tid < 32) {
        *(short8*)(WhT1 + (size_t)tid * N_NODES + row0) = *(const short8*)&t1[tid][0];
    } else if (tid < 96) {
        int q = tid - 32;          // 0..63
        int hh = q >> 1;           // 0..31
        int part = q & 1;          // 0..1
        *(float4*)(Wh2T + (size_t)hh * N_NODES + row0 + part * 4) = *(const float4*)&t2f[hh][part * 4];
    }
}

// ---------------------------------------------------------------------------
// Node 2 — merged: blocks 0..65 = per-channel bucket histogram + suffix scan
// (path 2, all in LDS -> Sc); blocks 66..577 = K2 path-1 MFMA attention.
// 512 threads, ~49.9 KB LDS union.
// ---------------------------------------------------------------------------
__global__ __launch_bounds__(512) void k2_scan(
    const float* __restrict__ s1g, const float* __restrict__ s2g,
    const unsigned short* __restrict__ WhT1, const float* __restrict__ Wh2T,
    const int* __restrict__ adj,
    float* __restrict__ num1, float* __restrict__ den1, float* __restrict__ Sc)
{
    __shared__ __align__(16) char smem[49920];
    int tid = threadIdx.x;
    int b = blockIdx.x;
    int lane = tid & 63;
    int wave = tid >> 6;

    if (b < NCH) {
        // ---- per-channel bucket histogram + suffix-inclusive scan ----
        float* hist = (float*)smem;            // 8192 floats = 32 KB
#pragma unroll
        for (int i = 0; i < 16; ++i) hist[tid + 512 * i] = 0.f;
        __syncthreads();

        int ch = b;
        const float* wcol = (ch < 32) ? (Wh2T + (size_t)ch * N_NODES)
                        : (ch < 64) ? (Wh2T + (size_t)(ch - 32) * N_NODES) : nullptr;
        const float kscale = (float)KB / (2.0f * RSH);
        bool useE = (ch < 32) || (ch == 64);
#pragma unroll 4
        for (int i = 0; i < 16; ++i) {
            int j = tid + 512 * i;
            float sv = s2g[j];
            int bi = (int)((sv + RSH) * kscale);
            bi = min(max(bi, 0), KB - 1);
            float ef = useE ? __expf(sv - RSH) : __expf(0.2f * (sv - RSH));
            float val = wcol ? ef * wcol[j] : ef;
            atomicAdd(&hist[bi], val);
        }
        __syncthreads();

        // suffix scan: thread t owns buckets [t*16, t*16+16)
        float v[16];
#pragma unroll
        for (int k = 0; k < 16; ++k) v[k] = hist[tid * 16 + k];
#pragma unroll
        for (int k = 14; k >= 0; --k) v[k] += v[k + 1];   // local suffix-inclusive
        float tot = v[0];
        float inc = tot;
#pragma unroll
        for (int d = 1; d < 64; d <<= 1) {
            float y = __shfl_down(inc, d);
            if (lane + d < 64) inc += y;
        }
        __shared__ float wt[8];
        if (lane == 0) wt[wave] = inc;     // whole-wave total
        __syncthreads();
        float woff = 0.f;
        for (int w = wave + 1; w < 8; ++w) woff += wt[w];
        float ex = (inc - tot) + woff;     // exclusive suffix from higher threads
        float* dst = Sc + (size_t)ch * KB + tid * 16;
        float4 o0 = make_float4(v[0] + ex,  v[1] + ex,  v[2] + ex,  v[3] + ex);
        float4 o1 = make_float4(v[4] + ex,  v[5] + ex,  v[6] + ex,  v[7] + ex);
        float4 o2 = make_float4(v[8] + ex,  v[9] + ex,  v[10] + ex, v[11] + ex);
        float4 o3 = make_float4(v[12] + ex, v[13] + ex, v[14] + ex, v[15] + ex);
        ((float4*)dst)[0] = o0; ((float4*)dst)[1] = o1;
        ((float4*)dst)[2] = o2; ((float4*)dst)[3] = o3;
        return;
    }

    // ---- K2: path-1 MFMA attention (round-6/11 body) ----
    unsigned short (*w_lds)[64 * 128] = (unsigned short (*)[64 * 128])smem;           // 2 x 16 KB
    unsigned short (*t_lds)[32 * 128] = (unsigned short (*)[32 * 128])(smem + 32768); // 2 x 8 KB
    float* srow = (float*)(smem + 49152);
    float* g1r  = (float*)(smem + 49408);
    float* g2r  = (float*)(smem + 49664);

    int kb2 = b - NCH;                 // 0..511
    int row0 = (kb2 >> 2) * 64;
    int jb = kb2 & 3;
    int jstart = jb * 2048;
    const float M0 = RSH;

    if (tid < 64) {
        float sv = s1g[row0 + tid];
        srow[tid] = sv;
        float u = sv + M0;
        g1r[tid] = u >= 0.f ? 1.f : __expf(0.8f * u);
        g2r[tid] = u >= 0.f ? __expf(-0.8f * u) : 1.f;
    }
    __syncthreads();

    int rg = wave >> 1;
    int hg = wave & 1;
    int grp = lane >> 4;

    int arow = rg * 16 + (lane & 15);
    int aswz = (arow & 7) << 4;
    int a_base = arow * 256;
    int brow = hg * 16 + (lane & 15);
    int bswz = (brow & 7) << 4;
    int b_base = brow * 256;

    int sh = tid >> 4, sc = tid & 15;
    int s_byte = (sh * 256 + sc * 16) ^ ((sh & 7) << 4);
    const unsigned short* src1 = WhT1 + (size_t)sh * N_NODES + sc * 8;

    int tcol = (tid & 31) * 4;
    int trh = tid >> 5;
    const int* adjb = adj + (size_t)row0 * N_NODES + tcol;

    f32x4 acc1 = {0.f, 0.f, 0.f, 0.f};
    float l0 = 0.f, l1 = 0.f, l2 = 0.f, l3 = 0.f;

    int4 cA, cB, cC, cD, nA, nB, nC, nD;
    float4 sj, e4, f4;

#define W_GEN(KK, AV, LL, WB)                                                   \
        {                                                                       \
            int r = KK * 16 + trh;                                              \
            float sr = srow[r], g1v = g1r[r], g2v = g2r[r];                     \
            bool px = sr + sj.x >= 0.f, py = sr + sj.y >= 0.f;                  \
            bool pz = sr + sj.z >= 0.f, pw = sr + sj.w >= 0.f;                  \
            float wx = (px ? g1v : g2v) * (px ? e4.x : f4.x);                   \
            float wy = (py ? g1v : g2v) * (py ? e4.y : f4.y);                   \
            float wz = (pz ? g1v : g2v) * (pz ? e4.z : f4.z);                   \
            float ww = (pw ? g1v : g2v) * (pw ? e4.w : f4.w);                   \
            if (AV.x == 0) wx = 0.f;                                            \
            if (AV.y == 0) wy = 0.f;                                            \
            if (AV.z == 0) wz = 0.f;                                            \
            if (AV.w == 0) ww = 0.f;                                            \
            LL += (wx + wy) + (wz + ww);                                        \
            uint2 pk;                                                           \
            pk.x = pack_bf_pair(wx, wy);                                        \
            pk.y = pack_bf_pair(wz, ww);                                        \
            int byte = (r * 256 + tcol * 2) ^ ((r & 7) << 4);                   \
            *(uint2*)((char*)(WB) + byte) = pk;                                 \
        }

#define EF_GEN(J0)                                                              \
        {                                                                       \
            sj = *(const float4*)(s1g + (J0) + tcol);                           \
            e4.x = __expf(sj.x - M0); e4.y = __expf(sj.y - M0);                 \
            e4.z = __expf(sj.z - M0); e4.w = __expf(sj.w - M0);                 \
            f4.x = __expf(0.2f * (sj.x - M0)); f4.y = __expf(0.2f * (sj.y - M0)); \
            f4.z = __expf(0.2f * (sj.z - M0)); f4.w = __expf(0.2f * (sj.w - M0)); \
        }

#define ADJ_LOAD(DA, DB, DC, DD, J0)                                            \
        {                                                                       \
            DA = *(const int4*)(adjb + (size_t)(0 * 16 + trh) * N_NODES + (J0)); \
            DB = *(const int4*)(adjb + (size_t)(1 * 16 + trh) * N_NODES + (J0)); \
            DC = *(const int4*)(adjb + (size_t)(2 * 16 + trh) * N_NODES + (J0)); \
            DD = *(const int4*)(adjb + (size_t)(3 * 16 + trh) * N_NODES + (J0)); \
        }

    // ---- prologue: tile 0 into buf0; preload adjacency tile 1 ----
    ADJ_LOAD(cA, cB, cC, cD, jstart)
    {
        short8 whv = *(const short8*)(src1 + jstart);
        *(short8*)((char*)t_lds[0] + s_byte) = whv;
    }
    EF_GEN(jstart)
    W_GEN(0, cA, l0, w_lds[0])
    W_GEN(1, cB, l1, w_lds[0])
    W_GEN(2, cC, l2, w_lds[0])
    W_GEN(3, cD, l3, w_lds[0])
    ADJ_LOAD(cA, cB, cC, cD, jstart + 128)

    int cur = 0;
    for (int jt = 0; jt < 16; ++jt) {
        __syncthreads();
        int nb = cur ^ 1;
        short8 whv;

        if (jt < 14) {
            ADJ_LOAD(nA, nB, nC, nD, jstart + (jt + 2) * 128)
        }
        if (jt < 15) {
            whv = *(const short8*)(src1 + jstart + (jt + 1) * 128);
            EF_GEN(jstart + (jt + 1) * 128)
        }

        {
            const char* wb = (const char*)w_lds[cur];
            const char* tb = (const char*)t_lds[cur];
#pragma unroll
            for (int ks = 0; ks < 4; ++ks) {
                short8 a = *(const short8*)(wb + ((a_base + ks * 64 + grp * 16) ^ aswz));
                short8 bv = *(const short8*)(tb + ((b_base + ks * 64 + grp * 16) ^ bswz));
                acc1 = __builtin_amdgcn_mfma_f32_16x16x32_bf16(a, bv, acc1, 0, 0, 0);
            }
        }

        if (jt < 15) {
            *(short8*)((char*)t_lds[nb] + s_byte) = whv;
            W_GEN(0, cA, l0, w_lds[nb])
            W_GEN(1, cB, l1, w_lds[nb])
            W_GEN(2, cC, l2, w_lds[nb])
            W_GEN(3, cD, l3, w_lds[nb])
            if (jt < 14) { cA = nA; cB = nB; cC = nC; cD = nD; }
        }
        cur = nb;
    }
#undef W_GEN
#undef EF_GEN
#undef ADJ_LOAD

#pragma unroll
    for (int reg = 0; reg < 4; ++reg) {
        int grow = row0 + rg * 16 + grp * 4 + reg;
        num1[((size_t)jb * N_NODES + grow) * 32 + hg * 16 + (lane & 15)] = acc1[reg];
    }

#define DEN(KK, DD)                                                             \
    {                                                                           \
        float d = DD;                                                           \
        d += __shfl_xor(d, 1);                                                  \
        d += __shfl_xor(d, 2);                                                  \
        d += __shfl_xor(d, 4);                                                  \
        d += __shfl_xor(d, 8);                                                  \
        d += __shfl_xor(d, 16);                                                 \
        if ((tid & 31) == 0) {                                                  \
            int r = KK * 16 + trh;                                              \
            den1[(size_t)jb * N_NODES + row0 + r] = d;                          \
        }                                                                       \
    }
    DEN(0, l0)
    DEN(1, l1)
    DEN(2, l2)
    DEN(3, l3)
#undef DEN
}

// ---------------------------------------------------------------------------
// Node 3 — K2b3: z1 from num1/den1; z2 from bucket suffix scans; semantic
// score partials via atomicAdd into wsum[2] (single fused pass).
// grid 1024 x 256 (8 rows x 32 h).
// ---------------------------------------------------------------------------
__global__ __launch_bounds__(256) void k2b3(
    const float* __restrict__ num1, const float* __restrict__ den1,
    const float* __restrict__ Sc, const float* __restrict__ s2g,
    const float* __restrict__ Wsw, const float* __restrict__ Wsb,
    const float* __restrict__ bsem, const float* __restrict__ q,
    float* __restrict__ z1, float* __restrict__ z2, float* __restrict__ wsum)
{
    __shared__ float zl1[256], zl2[256];
    __shared__ float rowsum0[8], rowsum1[8];
    int tid = threadIdx.x;
    int row0 = blockIdx.x * 8;
    int r = tid >> 5, h = tid & 31;
    int row = row0 + r;

    float n1 = 0.f, dd1 = 0.f;
#pragma unroll
    for (int jb = 0; jb < 4; ++jb) {
        n1 += num1[((size_t)jb * N_NODES + row) * 32 + h];
        dd1 += den1[(size_t)jb * N_NODES + row];
    }
    float z1v = sigmoidf_(dd1 > 0.f ? n1 / dd1 : 0.f);

    float sv = s2g[row];
    int bt = (int)roundf((RSH - sv) * ((float)KB / (2.0f * RSH)));
    bt = min(max(bt, 0), KB);
    float u = sv + RSH;
    float g1 = u >= 0.f ? 1.f : __expf(0.8f * u);
    float g2 = u >= 0.f ? __expf(-0.8f * u) : 1.f;

#define GATHER(CH, B) ((B) >= KB ? 0.f : Sc[(size_t)(CH) * KB + (B)])
    float SufE  = GATHER(h, bt);
    float SufF  = GATHER(32 + h, bt);
    float TotF  = GATHER(32 + h, 0);
    float SufEs = GATHER(64, bt);
    float SufFs = GATHER(65, bt);
    float TotFs = GATHER(65, 0);
#undef GATHER
    float num2 = g1 * SufE + g2 * (TotF - SufF);
    float den2 = g1 * SufEs + g2 * (TotFs - SufFs);
    float z2v = sigmoidf_(num2 / fmaxf(den2, 1e-37f));

    size_t gi = (size_t)row * H + h;
    z1[gi] = z1v;
    z2[gi] = z2v;
    zl1[tid] = z1v;
    zl2[tid] = z2v;
    __syncthreads();

    // fused semantic-score pass for both paths
    const float* wr = Wsw + h * H;
    const float* zr1 = zl1 + r * H;
    const float* zr2 = zl2 + r * H;
    float d0 = 0.f, d1p = 0.f;
#pragma unroll
    for (int k = 0; k < H; ++k) { d0 += zr1[k] * wr[k]; d1p += zr2[k] * wr[k]; }
    float bias = Wsb[h] + bsem[h];
    float qv = q[h];
    float val0 = tanh_fast(d0 + bias) * qv;
    float val1 = tanh_fast(d1p + bias) * qv;
#pragma unroll
    for (int m = 16; m >= 1; m >>= 1) {
        val0 += __shfl_xor(val0, m);
        val1 += __shfl_xor(val1, m);
    }
    if (h == 0) { rowsum0[r] = val0; rowsum1[r] = val1; }
    __syncthreads();
    if (tid == 0) {
        float s0 = 0.f, s1s = 0.f;
#pragma unroll
        for (int i = 0; i < 8; ++i) { s0 += rowsum0[i]; s1s += rowsum1[i]; }
        atomicAdd(&wsum[0], s0);
        atomicAdd(&wsum[1], s1s);
    }
}

// ---------------------------------------------------------------------------
// Node 4 — K4: beta from wsum (2 loads) + z_final + logits
// ---------------------------------------------------------------------------
__global__ __launch_bounds__(256) void k4_final(
    const float* __restrict__ z1, const float* __restrict__ z2,
    const float* __restrict__ wsum,
    const float* __restrict__ clsw, const float* __restrict__ clsb,
    float* __restrict__ out)
{
    int tid = threadIdx.x;
    float a = wsum[0] / (float)N_NODES;
    float b = wsum[1] / (float)N_NODES;
    float mx = fmaxf(a, b);
    float e0 = __expf(a - mx), e1 = __expf(b - mx);
    float inv = 1.f / (e0 + e1);
    float be0 = e0 * inv, be1 = e1 * inv;

    int row0 = blockIdx.x * 8;
    int r = tid >> 5, h = tid & 31;
    int grow = row0 + r;
    size_t gi = (size_t)grow * H + h;
    float zf = be0 * z1[gi] + be1 * z2[gi];
    out[gi] = zf;
    float p0 = zf * clsw[h];
    float p1 = zf * clsw[H + h];
#pragma unroll
    for (int m = 16; m >= 1; m >>= 1) { p0 += __shfl_xor(p0, m); p1 += __shfl_xor(p1, m); }
    if (h == 0) {
        out[(size_t)N_NODES * H + (size_t)grow * 2]     = p0 + clsb[0];
        out[(size_t)N_NODES * H + (size_t)grow * 2 + 1] = p1 + clsb[1];
    }
}

extern "C" void kernel_launch(void* const* d_in, const int* in_sizes, int n_in,
                              void* d_out, int out_size, void* d_ws, size_t ws_size,
                              hipStream_t stream)
{
    const float* x    = (const float*)d_in[0];
    const float* W1   = (const float*)d_in[1];
    const float* b1   = (const float*)d_in[2];
    const float* a1   = (const float*)d_in[3];
    const float* W2   = (const float*)d_in[4];
    const float* b2   = (const float*)d_in[5];
    const float* a2   = (const float*)d_in[6];
    const float* q    = (const float*)d_in[7];
    const float* Wsw  = (const float*)d_in[8];
    const float* Wsb  = (const float*)d_in[9];
    const float* bsem = (const float*)d_in[10];
    const float* clsw = (const float*)d_in[11];
    const float* clsb = (const float*)d_in[12];
    const int*   adj  = (const int*)d_in[13];
    // d_in[14] = mg_adj : unused

    // Workspace layout in FLOAT units.
    float* ws = (float*)d_ws;
    unsigned short* WhT1 = (unsigned short*)ws;        // floats [0, 131072) (bf16 H x N)
    float* Wh2T   = ws + 131072;                       // 262144 (f32 H x N)
    float* s1     = ws + 393216;                       // 8192
    float* s2     = s1 + N_NODES;                      // 8192
    float* wsum   = s2 + N_NODES;                      // 64 reserved (2 used)
    float* z1     = wsum + 64;                         // 262144
    float* z2     = z1 + N_NODES * H;                  // 262144
    float* num1   = z2 + N_NODES * H;                  // 4*8192*32 = 1048576
    float* den1   = num1 + 4 * N_NODES * 32;           // 4*8192 = 32768
    float* Sc     = den1 + 4 * N_NODES;                // 66*8192 = 540672
    // total ~= 10 MB

    float* out = (float*)d_out;

    hipLaunchKernelGGL(k1_wh_s, dim3(1024), dim3(256), 0, stream,
                       x, W1, b1, a1, W2, b2, a2, WhT1, Wh2T, s1, s2, wsum);

    hipLaunchKernelGGL(k2_scan, dim3(NCH + 512), dim3(512), 0, stream,
                       s1, s2, WhT1, Wh2T, adj, num1, den1, Sc);

    hipLaunchKernelGGL(k2b3, dim3(1024), dim3(256), 0, stream,
                       num1, den1, Sc, s2, Wsw, Wsb, bsem, q, z1, z2, wsum);

    hipLaunchKernelGGL(k4_final, dim3(1024), dim3(256), 0, stream,
                       z1, z2, wsum, clsw, clsb, out);
}

// Round 14
// 104.613 us; speedup vs baseline: 1.1639x; 1.1639x over previous
//
#include <hip/hip_runtime.h>
#include <cstdint>
#include <cstddef>

#define N_NODES 8192
#define IN_DIM 128
#define H 32
#define KB 8192          // path-2 buckets
#define NCH 66           // 32 E*Wh + 32 F*Wh + E + F channels
#define RSH 32.0f        // conservative shift: |s| << 32 by construction

typedef __attribute__((ext_vector_type(8))) short short8;
typedef __attribute__((ext_vector_type(4))) float f32x4;

__device__ __forceinline__ float sigmoidf_(float x) { return 1.0f / (1.0f + __expf(-x)); }
__device__ __forceinline__ float tanh_fast(float x) { return 1.0f - 2.0f / (1.0f + __expf(2.0f * x)); }
__device__ __forceinline__ unsigned short f2bf(float f) {
    unsigned u = __float_as_uint(f);
    unsigned r = (u + 0x7fffu + ((u >> 16) & 1u)) >> 16;
    return (unsigned short)r;
}
__device__ __forceinline__ unsigned pack_bf_pair(float lo, float hi) {
    unsigned a = __float_as_uint(lo) + 0x7FFFu;
    unsigned b = __float_as_uint(hi) + 0x7FFFu;
    return __builtin_amdgcn_perm(b, a, 0x07060302u);
}

// ---------------------------------------------------------------------------
// Node 1 — K1: Wh = x@W^T + b both paths. WhT1 bf16 (H x N) for MFMA;
// Wh2T f32 (H x N, for coalesced channel-scan reads); s = Wh@a.
// ---------------------------------------------------------------------------
__global__ __launch_bounds__(256) void k1_wh_s(
    const float* __restrict__ x,
    const float* __restrict__ W1, const float* __restrict__ b1, const float* __restrict__ a1,
    const float* __restrict__ W2, const float* __restrict__ b2, const float* __restrict__ a2,
    unsigned short* __restrict__ WhT1, float* __restrict__ Wh2T,
    float* __restrict__ s1, float* __restrict__ s2)
{
    __shared__ float xl[8 * IN_DIM];
    __shared__ __align__(16) unsigned short t1[32][8];
    __shared__ __align__(16) float t2f[32][8];
    int tid = threadIdx.x;
    int row0 = blockIdx.x * 8;

    ((float4*)xl)[tid] = ((const float4*)(x + (size_t)row0 * IN_DIM))[tid];
    __syncthreads();

    int r = tid >> 5, h = tid & 31;
    const float* xr = xl + r * IN_DIM;
    const float* w1r = W1 + h * IN_DIM;
    const float* w2r = W2 + h * IN_DIM;
    float d1 = 0.f, d2 = 0.f;
#pragma unroll 8
    for (int k = 0; k < IN_DIM; k += 4) {
        float4 xv = *(const float4*)(xr + k);
        float4 wa = *(const float4*)(w1r + k);
        float4 wb = *(const float4*)(w2r + k);
        d1 += xv.x * wa.x + xv.y * wa.y + xv.z * wa.z + xv.w * wa.w;
        d2 += xv.x * wb.x + xv.y * wb.y + xv.z * wb.z + xv.w * wb.w;
    }
    int grow = row0 + r;
    float wh1 = d1 + b1[h];
    float wh2 = d2 + b2[h];
    t1[h][r] = f2bf(wh1);
    t2f[h][r] = wh2;

    float v1 = wh1 * a1[h];
    float v2 = wh2 * a2[h];
#pragma unroll
    for (int m = 16; m >= 1; m >>= 1) { v1 += __shfl_xor(v1, m); v2 += __shfl_xor(v2, m); }
    if (h == 0) { s1[grow] = v1; s2[grow] = v2; }
    __syncthreads();

    if (tid < 32) {
        *(short8*)(WhT1 + (size_t)tid * N_NODES + row0) = *(const short8*)&t1[tid][0];
    } else if (tid < 96) {
        int q = tid - 32;          // 0..63
        int hh = q >> 1;           // 0..31
        int part = q & 1;          // 0..1
        *(float4*)(Wh2T + (size_t)hh * N_NODES + row0 + part * 4) = *(const float4*)&t2f[hh][part * 4];
    }
}

// ---------------------------------------------------------------------------
// Node 2 — merged: blocks 0..65 = per-channel bucket histogram + suffix scan
// (path 2, all in LDS -> Sc); blocks 66..577 = K2 path-1 MFMA attention.
// 512 threads, ~49.9 KB LDS union.
// ---------------------------------------------------------------------------
__global__ __launch_bounds__(512) void k2_scan(
    const float* __restrict__ s1g, const float* __restrict__ s2g,
    const unsigned short* __restrict__ WhT1, const float* __restrict__ Wh2T,
    const int* __restrict__ adj,
    float* __restrict__ num1, float* __restrict__ den1, float* __restrict__ Sc)
{
    __shared__ __align__(16) char smem[49920];
    int tid = threadIdx.x;
    int b = blockIdx.x;
    int lane = tid & 63;
    int wave = tid >> 6;

    if (b < NCH) {
        // ---- per-channel bucket histogram + suffix-inclusive scan ----
        float* hist = (float*)smem;            // 8192 floats = 32 KB
#pragma unroll
        for (int i = 0; i < 16; ++i) hist[tid + 512 * i] = 0.f;
        __syncthreads();

        int ch = b;
        const float* wcol = (ch < 32) ? (Wh2T + (size_t)ch * N_NODES)
                        : (ch < 64) ? (Wh2T + (size_t)(ch - 32) * N_NODES) : nullptr;
        const float kscale = (float)KB / (2.0f * RSH);
        bool useE = (ch < 32) || (ch == 64);
#pragma unroll 4
        for (int i = 0; i < 16; ++i) {
            int j = tid + 512 * i;
            float sv = s2g[j];
            int bi = (int)((sv + RSH) * kscale);
            bi = min(max(bi, 0), KB - 1);
            float ef = useE ? __expf(sv - RSH) : __expf(0.2f * (sv - RSH));
            float val = wcol ? ef * wcol[j] : ef;
            atomicAdd(&hist[bi], val);
        }
        __syncthreads();

        // suffix scan: thread t owns buckets [t*16, t*16+16)
        float v[16];
#pragma unroll
        for (int k = 0; k < 16; ++k) v[k] = hist[tid * 16 + k];
#pragma unroll
        for (int k = 14; k >= 0; --k) v[k] += v[k + 1];   // local suffix-inclusive
        float tot = v[0];
        float inc = tot;
#pragma unroll
        for (int d = 1; d < 64; d <<= 1) {
            float y = __shfl_down(inc, d);
            if (lane + d < 64) inc += y;
        }
        __shared__ float wt[8];
        if (lane == 0) wt[wave] = inc;     // whole-wave total
        __syncthreads();
        float woff = 0.f;
        for (int w = wave + 1; w < 8; ++w) woff += wt[w];
        float ex = (inc - tot) + woff;     // exclusive suffix from higher threads
        float* dst = Sc + (size_t)ch * KB + tid * 16;
        float4 o0 = make_float4(v[0] + ex,  v[1] + ex,  v[2] + ex,  v[3] + ex);
        float4 o1 = make_float4(v[4] + ex,  v[5] + ex,  v[6] + ex,  v[7] + ex);
        float4 o2 = make_float4(v[8] + ex,  v[9] + ex,  v[10] + ex, v[11] + ex);
        float4 o3 = make_float4(v[12] + ex, v[13] + ex, v[14] + ex, v[15] + ex);
        ((float4*)dst)[0] = o0; ((float4*)dst)[1] = o1;
        ((float4*)dst)[2] = o2; ((float4*)dst)[3] = o3;
        return;
    }

    // ---- K2: path-1 MFMA attention (round-6/11 body) ----
    unsigned short (*w_lds)[64 * 128] = (unsigned short (*)[64 * 128])smem;           // 2 x 16 KB
    unsigned short (*t_lds)[32 * 128] = (unsigned short (*)[32 * 128])(smem + 32768); // 2 x 8 KB
    float* srow = (float*)(smem + 49152);
    float* g1r  = (float*)(smem + 49408);
    float* g2r  = (float*)(smem + 49664);

    int kb2 = b - NCH;                 // 0..511
    int row0 = (kb2 >> 2) * 64;
    int jb = kb2 & 3;
    int jstart = jb * 2048;
    const float M0 = RSH;

    if (tid < 64) {
        float sv = s1g[row0 + tid];
        srow[tid] = sv;
        float u = sv + M0;
        g1r[tid] = u >= 0.f ? 1.f : __expf(0.8f * u);
        g2r[tid] = u >= 0.f ? __expf(-0.8f * u) : 1.f;
    }
    __syncthreads();

    int rg = wave >> 1;
    int hg = wave & 1;
    int grp = lane >> 4;

    int arow = rg * 16 + (lane & 15);
    int aswz = (arow & 7) << 4;
    int a_base = arow * 256;
    int brow = hg * 16 + (lane & 15);
    int bswz = (brow & 7) << 4;
    int b_base = brow * 256;

    int sh = tid >> 4, sc = tid & 15;
    int s_byte = (sh * 256 + sc * 16) ^ ((sh & 7) << 4);
    const unsigned short* src1 = WhT1 + (size_t)sh * N_NODES + sc * 8;

    int tcol = (tid & 31) * 4;
    int trh = tid >> 5;
    const int* adjb = adj + (size_t)row0 * N_NODES + tcol;

    f32x4 acc1 = {0.f, 0.f, 0.f, 0.f};
    float l0 = 0.f, l1 = 0.f, l2 = 0.f, l3 = 0.f;

    int4 cA, cB, cC, cD, nA, nB, nC, nD;
    float4 sj, e4, f4;

#define W_GEN(KK, AV, LL, WB)                                                   \
        {                                                                       \
            int r = KK * 16 + trh;                                              \
            float sr = srow[r], g1v = g1r[r], g2v = g2r[r];                     \
            bool px = sr + sj.x >= 0.f, py = sr + sj.y >= 0.f;                  \
            bool pz = sr + sj.z >= 0.f, pw = sr + sj.w >= 0.f;                  \
            float wx = (px ? g1v : g2v) * (px ? e4.x : f4.x);                   \
            float wy = (py ? g1v : g2v) * (py ? e4.y : f4.y);                   \
            float wz = (pz ? g1v : g2v) * (pz ? e4.z : f4.z);                   \
            float ww = (pw ? g1v : g2v) * (pw ? e4.w : f4.w);                   \
            if (AV.x == 0) wx = 0.f;                                            \
            if (AV.y == 0) wy = 0.f;                                            \
            if (AV.z == 0) wz = 0.f;                                            \
            if (AV.w == 0) ww = 0.f;                                            \
            LL += (wx + wy) + (wz + ww);                                        \
            uint2 pk;                                                           \
            pk.x = pack_bf_pair(wx, wy);                                        \
            pk.y = pack_bf_pair(wz, ww);                                        \
            int byte = (r * 256 + tcol * 2) ^ ((r & 7) << 4);                   \
            *(uint2*)((char*)(WB) + byte) = pk;                                 \
        }

#define EF_GEN(J0)                                                              \
        {                                                                       \
            sj = *(const float4*)(s1g + (J0) + tcol);                           \
            e4.x = __expf(sj.x - M0); e4.y = __expf(sj.y - M0);                 \
            e4.z = __expf(sj.z - M0); e4.w = __expf(sj.w - M0);                 \
            f4.x = __expf(0.2f * (sj.x - M0)); f4.y = __expf(0.2f * (sj.y - M0)); \
            f4.z = __expf(0.2f * (sj.z - M0)); f4.w = __expf(0.2f * (sj.w - M0)); \
        }

#define ADJ_LOAD(DA, DB, DC, DD, J0)                                            \
        {                                                                       \
            DA = *(const int4*)(adjb + (size_t)(0 * 16 + trh) * N_NODES + (J0)); \
            DB = *(const int4*)(adjb + (size_t)(1 * 16 + trh) * N_NODES + (J0)); \
            DC = *(const int4*)(adjb + (size_t)(2 * 16 + trh) * N_NODES + (J0)); \
            DD = *(const int4*)(adjb + (size_t)(3 * 16 + trh) * N_NODES + (J0)); \
        }

    // ---- prologue: tile 0 into buf0; preload adjacency tile 1 ----
    ADJ_LOAD(cA, cB, cC, cD, jstart)
    {
        short8 whv = *(const short8*)(src1 + jstart);
        *(short8*)((char*)t_lds[0] + s_byte) = whv;
    }
    EF_GEN(jstart)
    W_GEN(0, cA, l0, w_lds[0])
    W_GEN(1, cB, l1, w_lds[0])
    W_GEN(2, cC, l2, w_lds[0])
    W_GEN(3, cD, l3, w_lds[0])
    ADJ_LOAD(cA, cB, cC, cD, jstart + 128)

    int cur = 0;
    for (int jt = 0; jt < 16; ++jt) {
        __syncthreads();
        int nb = cur ^ 1;
        short8 whv;

        if (jt < 14) {
            ADJ_LOAD(nA, nB, nC, nD, jstart + (jt + 2) * 128)
        }
        if (jt < 15) {
            whv = *(const short8*)(src1 + jstart + (jt + 1) * 128);
            EF_GEN(jstart + (jt + 1) * 128)
        }

        {
            const char* wb = (const char*)w_lds[cur];
            const char* tb = (const char*)t_lds[cur];
#pragma unroll
            for (int ks = 0; ks < 4; ++ks) {
                short8 a = *(const short8*)(wb + ((a_base + ks * 64 + grp * 16) ^ aswz));
                short8 bv = *(const short8*)(tb + ((b_base + ks * 64 + grp * 16) ^ bswz));
                acc1 = __builtin_amdgcn_mfma_f32_16x16x32_bf16(a, bv, acc1, 0, 0, 0);
            }
        }

        if (jt < 15) {
            *(short8*)((char*)t_lds[nb] + s_byte) = whv;
            W_GEN(0, cA, l0, w_lds[nb])
            W_GEN(1, cB, l1, w_lds[nb])
            W_GEN(2, cC, l2, w_lds[nb])
            W_GEN(3, cD, l3, w_lds[nb])
            if (jt < 14) { cA = nA; cB = nB; cC = nC; cD = nD; }
        }
        cur = nb;
    }
#undef W_GEN
#undef EF_GEN
#undef ADJ_LOAD

#pragma unroll
    for (int reg = 0; reg < 4; ++reg) {
        int grow = row0 + rg * 16 + grp * 4 + reg;
        num1[((size_t)jb * N_NODES + grow) * 32 + hg * 16 + (lane & 15)] = acc1[reg];
    }

#define DEN(KK, DD)                                                             \
    {                                                                           \
        float d = DD;                                                           \
        d += __shfl_xor(d, 1);                                                  \
        d += __shfl_xor(d, 2);                                                  \
        d += __shfl_xor(d, 4);                                                  \
        d += __shfl_xor(d, 8);                                                  \
        d += __shfl_xor(d, 16);                                                 \
        if ((tid & 31) == 0) {                                                  \
            int r = KK * 16 + trh;                                              \
            den1[(size_t)jb * N_NODES + row0 + r] = d;                          \
        }                                                                       \
    }
    DEN(0, l0)
    DEN(1, l1)
    DEN(2, l2)
    DEN(3, l3)
#undef DEN
}

// ---------------------------------------------------------------------------
// Node 3 — K2b3: z1 from num1/den1; z2 from bucket suffix scans; semantic
// score partials. grid 1024 x 256 (8 rows x 32 h).
// ---------------------------------------------------------------------------
__global__ __launch_bounds__(256) void k2b3(
    const float* __restrict__ num1, const float* __restrict__ den1,
    const float* __restrict__ Sc, const float* __restrict__ s2g,
    const float* __restrict__ Wsw, const float* __restrict__ Wsb,
    const float* __restrict__ bsem, const float* __restrict__ q,
    float* __restrict__ z1, float* __restrict__ z2, float* __restrict__ partial)
{
    __shared__ float zl1[256], zl2[256];
    __shared__ float rowsum[8];
    int tid = threadIdx.x;
    int row0 = blockIdx.x * 8;
    int r = tid >> 5, h = tid & 31;
    int row = row0 + r;

    float n1 = 0.f, d1 = 0.f;
#pragma unroll
    for (int jb = 0; jb < 4; ++jb) {
        n1 += num1[((size_t)jb * N_NODES + row) * 32 + h];
        d1 += den1[(size_t)jb * N_NODES + row];
    }
    float z1v = sigmoidf_(d1 > 0.f ? n1 / d1 : 0.f);

    float sv = s2g[row];
    int bt = (int)roundf((RSH - sv) * ((float)KB / (2.0f * RSH)));
    bt = min(max(bt, 0), KB);
    float u = sv + RSH;
    float g1 = u >= 0.f ? 1.f : __expf(0.8f * u);
    float g2 = u >= 0.f ? __expf(-0.8f * u) : 1.f;

#define GATHER(CH, B) ((B) >= KB ? 0.f : Sc[(size_t)(CH) * KB + (B)])
    float SufE  = GATHER(h, bt);
    float SufF  = GATHER(32 + h, bt);
    float TotF  = GATHER(32 + h, 0);
    float SufEs = GATHER(64, bt);
    float SufFs = GATHER(65, bt);
    float TotFs = GATHER(65, 0);
#undef GATHER
    float num2 = g1 * SufE + g2 * (TotF - SufF);
    float den2 = g1 * SufEs + g2 * (TotFs - SufFs);
    float z2v = sigmoidf_(num2 / fmaxf(den2, 1e-37f));

    size_t gi = (size_t)row * H + h;
    z1[gi] = z1v;
    z2[gi] = z2v;
    zl1[tid] = z1v;
    zl2[tid] = z2v;
    __syncthreads();

    const float* wr = Wsw + h * H;
    for (int p = 0; p < 2; ++p) {
        const float* zl = p ? zl2 : zl1;
        float d = 0.f;
        const float* zr = zl + r * H;
#pragma unroll
        for (int k = 0; k < H; ++k) d += zr[k] * wr[k];
        float val = tanh_fast(d + Wsb[h] + bsem[h]) * q[h];
#pragma unroll
        for (int m = 16; m >= 1; m >>= 1) val += __shfl_xor(val, m);
        if (h == 0) rowsum[r] = val;
        __syncthreads();
        if (tid == 0) {
            float s = 0.f;
#pragma unroll
            for (int i = 0; i < 8; ++i) s += rowsum[i];
            partial[p * 1024 + blockIdx.x] = s;
        }
        __syncthreads();
    }
}

// ---------------------------------------------------------------------------
// Node 4 — K4: beta (in-block reduction of partial) + z_final + logits
// ---------------------------------------------------------------------------
__global__ __launch_bounds__(256) void k4_final(
    const float* __restrict__ z1, const float* __restrict__ z2,
    const float* __restrict__ partial,
    const float* __restrict__ clsw, const float* __restrict__ clsb,
    float* __restrict__ out)
{
    __shared__ float red[8];
    int tid = threadIdx.x;

    float s1 = 0.f, s2 = 0.f;
    for (int i = tid; i < 1024; i += 256) { s1 += partial[i]; s2 += partial[1024 + i]; }
#pragma unroll
    for (int m = 32; m >= 1; m >>= 1) { s1 += __shfl_xor(s1, m); s2 += __shfl_xor(s2, m); }
    if ((tid & 63) == 0) { red[(tid >> 6) * 2] = s1; red[(tid >> 6) * 2 + 1] = s2; }
    __syncthreads();
    float a = (red[0] + red[2]) + (red[4] + red[6]);
    float b = (red[1] + red[3]) + (red[5] + red[7]);
    a /= (float)N_NODES;
    b /= (float)N_NODES;
    float mx = fmaxf(a, b);
    float e0 = __expf(a - mx), e1 = __expf(b - mx);
    float inv = 1.f / (e0 + e1);
    float be0 = e0 * inv, be1 = e1 * inv;

    int row0 = blockIdx.x * 8;
    int r = tid >> 5, h = tid & 31;
    int grow = row0 + r;
    size_t gi = (size_t)grow * H + h;
    float zf = be0 * z1[gi] + be1 * z2[gi];
    out[gi] = zf;
    float p0 = zf * clsw[h];
    float p1 = zf * clsw[H + h];
#pragma unroll
    for (int m = 16; m >= 1; m >>= 1) { p0 += __shfl_xor(p0, m); p1 += __shfl_xor(p1, m); }
    if (h == 0) {
        out[(size_t)N_NODES * H + (size_t)grow * 2]     = p0 + clsb[0];
        out[(size_t)N_NODES * H + (size_t)grow * 2 + 1] = p1 + clsb[1];
    }
}

extern "C" void kernel_launch(void* const* d_in, const int* in_sizes, int n_in,
                              void* d_out, int out_size, void* d_ws, size_t ws_size,
                              hipStream_t stream)
{
    const float* x    = (const float*)d_in[0];
    const float* W1   = (const float*)d_in[1];
    const float* b1   = (const float*)d_in[2];
    const float* a1   = (const float*)d_in[3];
    const float* W2   = (const float*)d_in[4];
    const float* b2   = (const float*)d_in[5];
    const float* a2   = (const float*)d_in[6];
    const float* q    = (const float*)d_in[7];
    const float* Wsw  = (const float*)d_in[8];
    const float* Wsb  = (const float*)d_in[9];
    const float* bsem = (const float*)d_in[10];
    const float* clsw = (const float*)d_in[11];
    const float* clsb = (const float*)d_in[12];
    const int*   adj  = (const int*)d_in[13];
    // d_in[14] = mg_adj : unused

    // Workspace layout in FLOAT units.
    float* ws = (float*)d_ws;
    unsigned short* WhT1 = (unsigned short*)ws;        // floats [0, 131072) (bf16 H x N)
    float* Wh2T   = ws + 131072;                       // 262144 (f32 H x N)
    float* s1     = ws + 393216;                       // 8192
    float* s2     = s1 + N_NODES;                      // 8192
    float* partial= s2 + N_NODES;                      // 2048
    float* z1     = partial + 2048;                    // 262144
    float* z2     = z1 + N_NODES * H;                  // 262144
    float* num1   = z2 + N_NODES * H;                  // 4*8192*32 = 1048576
    float* den1   = num1 + 4 * N_NODES * 32;           // 4*8192 = 32768
    float* Sc     = den1 + 4 * N_NODES;                // 66*8192 = 540672
    // total ~= 10 MB

    float* out = (float*)d_out;

    hipLaunchKernelGGL(k1_wh_s, dim3(1024), dim3(256), 0, stream,
                       x, W1, b1, a1, W2, b2, a2, WhT1, Wh2T, s1, s2);

    hipLaunchKernelGGL(k2_scan, dim3(NCH + 512), dim3(512), 0, stream,
                       s1, s2, WhT1, Wh2T, adj, num1, den1, Sc);

    hipLaunchKernelGGL(k2b3, dim3(1024), dim3(256), 0, stream,
                       num1, den1, Sc, s2, Wsw, Wsb, bsem, q, z1, z2, partial);

    hipLaunchKernelGGL(k4_final, dim3(1024), dim3(256), 0, stream,
                       z1, z2, partial, clsw, clsb, out);
}